// Round 1
// baseline (132.248 us; speedup 1.0000x reference)
//
#include <hip/hip_runtime.h>
#include <hip/hip_bf16.h>

// 3x3 s1 p1 conv: B=16, CIN=128, H=W=56, COUT=256.  K-dim = CIN*9 = 1152.
#define CIN_   128
#define HW_    56
#define LHW_   3136      // 56*56
#define COUT_  256
#define KTOT_  1152      // CIN*9
#define SPT_   64        // spatial tile per block (3136 % 64 == 0)
#define BK_    32        // K per step
#define NKS_   36        // 1152/32
#define LDSW_  40        // padded LDS row length in bf16 elems (80B, 16B-aligned)

typedef unsigned short u16;
typedef __attribute__((ext_vector_type(8))) short short8v;   // 8 bf16 = 4 VGPRs
typedef __attribute__((ext_vector_type(4))) float f32x4;

__device__ __forceinline__ u16 f2bf(float f) {
  union { float f; unsigned u; } v; v.f = f;
  unsigned u = v.u;
  u += 0x7fffu + ((u >> 16) & 1u);   // round-to-nearest-even
  return (u16)(u >> 16);
}

__global__ void wconvert_kernel(const float* __restrict__ w, u16* __restrict__ wb) {
  int i = blockIdx.x * 256 + threadIdx.x;       // 73728 threads == (256*1152)/4
  float4 f = reinterpret_cast<const float4*>(w)[i];
  ushort4 o;
  o.x = f2bf(f.x); o.y = f2bf(f.y); o.z = f2bf(f.z); o.w = f2bf(f.w);
  reinterpret_cast<ushort4*>(wb)[i] = o;
}

template<bool WB16>
__global__ __launch_bounds__(256, 2) void conv_kernel(
    const float* __restrict__ in, const void* __restrict__ wp,
    const float* __restrict__ bias, float* __restrict__ out)
{
  __shared__ u16 xs[SPT_ * LDSW_];

  const int tid  = threadIdx.x;
  const int lane = tid & 63;
  const int wid  = tid >> 6;        // wave id 0..3 -> cout slice of 64
  const int lg   = lane >> 4;       // 0..3 (k-subgroup of 8)
  const int lr   = lane & 15;

  const int bid = blockIdx.x;       // 784 blocks
  const int b   = bid / 49;         // batch (3136/64 = 49 tiles per image)
  const int l0  = (bid % 49) * SPT_;

  // staging mapping: thread -> (spatial sp, k-subchunk qq of 8)
  const int sp = tid & 63;
  const int qq = tid >> 6;
  const int l  = l0 + sp;
  const int y  = l / HW_;
  const int x  = l - y * HW_;
  const float* inb = in + (size_t)b * CIN_ * LHW_;

  f32x4 acc[4][4];
  #pragma unroll
  for (int i = 0; i < 4; ++i)
    #pragma unroll
    for (int j = 0; j < 4; ++j)
      acc[i][j] = f32x4{0.f, 0.f, 0.f, 0.f};

  // im2col staging load: 8 consecutive k values for (sp, qq), predicated halo.
  auto stage_load = [&](int ks) -> uint4 {
    int kbase = ks * BK_ + qq * 8;
    int c = kbase / 9;
    int t = kbase - c * 9;          // tap index 0..8
    u16 v[8];
    #pragma unroll
    for (int j = 0; j < 8; ++j) {
      int dy = (t * 11) >> 5;       // t/3 for t in [0,9)
      int dx = t - 3 * dy;
      int yy = y + dy - 1;
      int xx = x + dx - 1;
      float f = 0.f;
      if ((unsigned)yy < (unsigned)HW_ && (unsigned)xx < (unsigned)HW_)
        f = inb[(c * HW_ + yy) * HW_ + xx];
      v[j] = f2bf(f);
      ++t; if (t == 9) { t = 0; ++c; }
    }
    uint4 r;
    r.x = (unsigned)v[0] | ((unsigned)v[1] << 16);
    r.y = (unsigned)v[2] | ((unsigned)v[3] << 16);
    r.z = (unsigned)v[4] | ((unsigned)v[5] << 16);
    r.w = (unsigned)v[6] | ((unsigned)v[7] << 16);
    return r;
  };

  uint4 st = stage_load(0);

  const u16*   wb = (const u16*)wp;
  const float* wf = (const float*)wp;

  for (int ks = 0; ks < NKS_; ++ks) {
    __syncthreads();                                 // prev-tile reads done
    *reinterpret_cast<uint4*>(&xs[sp * LDSW_ + qq * 8]) = st;  // ds_write_b128
    __syncthreads();
    if (ks + 1 < NKS_) st = stage_load(ks + 1);      // issue next loads early (hide under MFMA)

    const int k0 = ks * BK_;

    short8v a[4];
    #pragma unroll
    for (int ai = 0; ai < 4; ++ai) {
      const int o = wid * 64 + ai * 16 + lr;
      if (WB16) {
        a[ai] = *reinterpret_cast<const short8v*>(wb + (size_t)o * KTOT_ + k0 + lg * 8);
      } else {
        const float* p = wf + (size_t)o * KTOT_ + k0 + lg * 8;
        u16 t8[8];
        #pragma unroll
        for (int j = 0; j < 8; ++j) t8[j] = f2bf(p[j]);
        union { uint4 u; short8v s; } cv;
        cv.u.x = (unsigned)t8[0] | ((unsigned)t8[1] << 16);
        cv.u.y = (unsigned)t8[2] | ((unsigned)t8[3] << 16);
        cv.u.z = (unsigned)t8[4] | ((unsigned)t8[5] << 16);
        cv.u.w = (unsigned)t8[6] | ((unsigned)t8[7] << 16);
        a[ai] = cv.s;
      }
    }

    short8v bv[4];
    #pragma unroll
    for (int sj = 0; sj < 4; ++sj)
      bv[sj] = *reinterpret_cast<const short8v*>(&xs[(sj * 16 + lr) * LDSW_ + lg * 8]);

    #pragma unroll
    for (int ai = 0; ai < 4; ++ai)
      #pragma unroll
      for (int sj = 0; sj < 4; ++sj)
        acc[ai][sj] = __builtin_amdgcn_mfma_f32_16x16x32_bf16(a[ai], bv[sj], acc[ai][sj], 0, 0, 0);
  }

  // Epilogue: D layout col = lane&15 (spatial), row = (lane>>4)*4 + reg (cout).
  float* outb = out + (size_t)b * COUT_ * LHW_ + l0;
  #pragma unroll
  for (int ai = 0; ai < 4; ++ai) {
    #pragma unroll
    for (int r = 0; r < 4; ++r) {
      const int o = wid * 64 + ai * 16 + lg * 4 + r;
      const float bvs = bias[o];
      #pragma unroll
      for (int sj = 0; sj < 4; ++sj)
        outb[(size_t)o * LHW_ + sj * 16 + lr] = acc[ai][sj][r] + bvs;
    }
  }
}

extern "C" void kernel_launch(void* const* d_in, const int* in_sizes, int n_in,
                              void* d_out, int out_size, void* d_ws, size_t ws_size,
                              hipStream_t stream) {
  (void)in_sizes; (void)n_in; (void)out_size;
  const float* in   = (const float*)d_in[0];
  const float* w    = (const float*)d_in[1];
  const float* bias = (const float*)d_in[2];
  float* out = (float*)d_out;

  const size_t wbytes = (size_t)COUT_ * KTOT_ * sizeof(u16);   // 589824
  if (ws_size >= wbytes) {
    u16* wb = (u16*)d_ws;
    wconvert_kernel<<<dim3(288), dim3(256), 0, stream>>>(w, wb);
    conv_kernel<true><<<dim3(784), dim3(256), 0, stream>>>(in, (const void*)wb, bias, out);
  } else {
    conv_kernel<false><<<dim3(784), dim3(256), 0, stream>>>(in, (const void*)w, bias, out);
  }
}

// Round 2
// 71.050 us; speedup vs baseline: 1.8613x; 1.8613x over previous
//
#include <hip/hip_runtime.h>
#include <hip/hip_bf16.h>

// 3x3 s1 p1 conv: B=16, CIN=128, H=W=56, COUT=256, K-dim = 9*128.
// Tap-major implicit GEMM: weights reordered to wb[t][o][c]; raw input tile
// staged once per block in XOR-swizzled LDS; barrier-free 9-tap MFMA loop.
#define CIN_   128
#define HW_    56
#define LHW_   3136
#define COUT_  256
#define KTOT_  1152
#define TH_    2         // output rows per block tile
#define SPT_   112       // TH*56 spatial positions per block
#define NF_    7         // spatial N-fragments (112/16)
#define SCOLS_ 58        // staged cols (56 + 2 zero-pad)
#define SPP_   232       // staged positions (TH+2)*58
#define CSTR_  128       // u16 per staged row (all channels)

typedef unsigned short u16;
typedef __attribute__((ext_vector_type(8))) short short8v;   // 8 bf16
typedef __attribute__((ext_vector_type(4))) float f32x4;

__device__ __forceinline__ u16 f2bf(float f) {
  union { float f; unsigned u; } v; v.f = f;
  unsigned u = v.u;
  u += 0x7fffu + ((u >> 16) & 1u);   // RNE
  return (u16)(u >> 16);
}
__device__ __forceinline__ unsigned pack2(u16 a, u16 b) {
  return (unsigned)a | ((unsigned)b << 16);
}

// wb[(t*256+o)*128 + c] = bf16(w[o][c*9+t])
__global__ void wreorder_kernel(const float* __restrict__ w, u16* __restrict__ wb) {
  int j = blockIdx.x * 256 + threadIdx.x;   // 73728 = 9*256*32
  int c4 = j & 31;
  int o  = (j >> 5) & 255;
  int t  = j >> 13;
  const float* src = w + (size_t)o * KTOT_ + t;
  ushort4 r;
  r.x = f2bf(src[(c4 * 4 + 0) * 9]);
  r.y = f2bf(src[(c4 * 4 + 1) * 9]);
  r.z = f2bf(src[(c4 * 4 + 2) * 9]);
  r.w = f2bf(src[(c4 * 4 + 3) * 9]);
  *reinterpret_cast<ushort4*>(wb + ((size_t)(t * 256 + o) * CSTR_ + c4 * 4)) = r;
}

__global__ __launch_bounds__(256, 2) void conv2_kernel(
    const float* __restrict__ in, const u16* __restrict__ wb,
    const float* __restrict__ bias, float* __restrict__ out)
{
  __shared__ u16 xs[SPP_ * CSTR_];   // 59392 B, XOR-swizzled rows of 256B

  const int tid  = threadIdx.x;
  const int lane = tid & 63;
  const int wid  = tid >> 6;     // wave -> 32-cout slice
  const int lr   = lane & 15;
  const int lg   = lane >> 4;

  const int bid = blockIdx.x;    // 896 = 16 b * 28 ty * 2 ch
  const int ch  = bid & 1;
  const int ty  = (bid >> 1) % 28;
  const int b   = bid / 56;

  const float* inb = in + (size_t)b * CIN_ * LHW_;
  const int iy0 = ty * TH_ - 1;

  // ---- stage raw input tile (fp32 -> bf16), one pass, swizzled ----
  #pragma unroll 1
  for (int i = 0; i < 15; ++i) {
    int idx = i * 256 + tid;             // 3712 tasks = 232 spp * 16 cgroups
    if (idx < SPP_ * 16) {
      int cg  = idx / SPP_;
      int spp = idx - cg * SPP_;
      int rr  = spp / SCOLS_;
      int cc  = spp - rr * SCOLS_;
      int iy  = iy0 + rr;
      int ix  = cc - 1;
      bool ok = ((unsigned)iy < (unsigned)HW_) && ((unsigned)ix < (unsigned)HW_);
      const float* p = inb + (size_t)cg * 8 * LHW_ + iy * HW_ + ix;
      u16 v[8];
      #pragma unroll
      for (int jj = 0; jj < 8; ++jj)
        v[jj] = f2bf(ok ? p[jj * LHW_] : 0.f);
      uint4 pk;
      pk.x = pack2(v[0], v[1]); pk.y = pack2(v[2], v[3]);
      pk.z = pack2(v[4], v[5]); pk.w = pack2(v[6], v[7]);
      *reinterpret_cast<uint4*>(&xs[spp * CSTR_ + ((cg * 8) ^ ((spp & 7) << 3))]) = pk;
    }
  }

  // per-lane staged-position base for each N fragment
  int spp0[NF_];
  #pragma unroll
  for (int nf = 0; nf < NF_; ++nf) {
    int sp = nf * 16 + lr;
    int r  = (sp >= 56) ? 1 : 0;
    int x  = sp - r * 56;
    spp0[nf] = (r + 1) * SCOLS_ + x + 1;
  }

  f32x4 acc[2][NF_];
  #pragma unroll
  for (int m = 0; m < 2; ++m)
    #pragma unroll
    for (int nf = 0; nf < NF_; ++nf)
      acc[m][nf] = f32x4{0.f, 0.f, 0.f, 0.f};

  __syncthreads();   // the only barrier

  const u16* wt0 = wb + (size_t)(ch * 128 + wid * 32 + lr) * CSTR_ + lg * 8;

  #pragma unroll 1
  for (int t = 0; t < 9; ++t) {
    const int dspp = (t / 3 - 1) * SCOLS_ + (t % 3 - 1);
    const u16* wt = wt0 + (size_t)t * 256 * CSTR_;
    #pragma unroll
    for (int c0i = 0; c0i < 4; ++c0i) {
      const int c0 = c0i * 32;
      short8v a0 = *reinterpret_cast<const short8v*>(wt + c0);
      short8v a1 = *reinterpret_cast<const short8v*>(wt + 16 * CSTR_ + c0);
      short8v bv[NF_];
      #pragma unroll
      for (int nf = 0; nf < NF_; ++nf) {
        int spp = spp0[nf] + dspp;
        int off = spp * CSTR_ + ((c0 + lg * 8) ^ ((spp & 7) << 3));
        bv[nf] = *reinterpret_cast<const short8v*>(&xs[off]);
      }
      #pragma unroll
      for (int nf = 0; nf < NF_; ++nf) {
        acc[0][nf] = __builtin_amdgcn_mfma_f32_16x16x32_bf16(a0, bv[nf], acc[0][nf], 0, 0, 0);
        acc[1][nf] = __builtin_amdgcn_mfma_f32_16x16x32_bf16(a1, bv[nf], acc[1][nf], 0, 0, 0);
      }
    }
  }

  // epilogue: D col = lane&15 (spatial), row = lg*4+reg (cout). Full-width
  // rows make spatial linear: out linear = ty*112 + sp.
  float* ob = out + (size_t)b * COUT_ * LHW_ + ty * SPT_;
  const int obase = ch * 128 + wid * 32 + lg * 4;
  #pragma unroll
  for (int m = 0; m < 2; ++m) {
    #pragma unroll
    for (int rr = 0; rr < 4; ++rr) {
      const int o = obase + m * 16 + rr;
      const float bs = bias[o];
      #pragma unroll
      for (int nf = 0; nf < NF_; ++nf)
        ob[(size_t)o * LHW_ + nf * 16 + lr] = acc[m][nf][rr] + bs;
    }
  }
}

// ---------------- fallback (ws too small): round-1 kernel, fp32 weights ----
#define SPT0_  64
#define BK0_   32
#define NKS0_  36
#define LDSW0_ 40

__global__ __launch_bounds__(256, 2) void conv_fb_kernel(
    const float* __restrict__ in, const float* __restrict__ wf,
    const float* __restrict__ bias, float* __restrict__ out)
{
  __shared__ u16 xs[SPT0_ * LDSW0_];
  const int tid = threadIdx.x;
  const int lane = tid & 63;
  const int wid = tid >> 6;
  const int lg = lane >> 4;
  const int lr = lane & 15;
  const int bid = blockIdx.x;
  const int b = bid / 49;
  const int l0 = (bid % 49) * SPT0_;
  const int sp = tid & 63;
  const int qq = tid >> 6;
  const int l = l0 + sp;
  const int y = l / HW_;
  const int x = l - y * HW_;
  const float* inb = in + (size_t)b * CIN_ * LHW_;

  f32x4 acc[4][4];
  #pragma unroll
  for (int i = 0; i < 4; ++i)
    #pragma unroll
    for (int j = 0; j < 4; ++j) acc[i][j] = f32x4{0.f, 0.f, 0.f, 0.f};

  auto stage_load = [&](int ks) -> uint4 {
    int kbase = ks * BK0_ + qq * 8;
    int c = kbase / 9;
    int t = kbase - c * 9;
    u16 v[8];
    #pragma unroll
    for (int j = 0; j < 8; ++j) {
      int dy = (t * 11) >> 5;
      int dx = t - 3 * dy;
      int yy = y + dy - 1, xx = x + dx - 1;
      float f = 0.f;
      if ((unsigned)yy < (unsigned)HW_ && (unsigned)xx < (unsigned)HW_)
        f = inb[(c * HW_ + yy) * HW_ + xx];
      v[j] = f2bf(f);
      ++t; if (t == 9) { t = 0; ++c; }
    }
    uint4 r;
    r.x = pack2(v[0], v[1]); r.y = pack2(v[2], v[3]);
    r.z = pack2(v[4], v[5]); r.w = pack2(v[6], v[7]);
    return r;
  };

  uint4 st = stage_load(0);
  for (int ks = 0; ks < NKS0_; ++ks) {
    __syncthreads();
    *reinterpret_cast<uint4*>(&xs[sp * LDSW0_ + qq * 8]) = st;
    __syncthreads();
    if (ks + 1 < NKS0_) st = stage_load(ks + 1);
    const int k0 = ks * BK0_;
    short8v a[4];
    #pragma unroll
    for (int ai = 0; ai < 4; ++ai) {
      const int o = wid * 64 + ai * 16 + lr;
      const float* p = wf + (size_t)o * KTOT_ + k0 + lg * 8;
      u16 t8[8];
      #pragma unroll
      for (int j = 0; j < 8; ++j) t8[j] = f2bf(p[j]);
      union { uint4 u; short8v s; } cv;
      cv.u.x = pack2(t8[0], t8[1]); cv.u.y = pack2(t8[2], t8[3]);
      cv.u.z = pack2(t8[4], t8[5]); cv.u.w = pack2(t8[6], t8[7]);
      a[ai] = cv.s;
    }
    short8v bv[4];
    #pragma unroll
    for (int sj = 0; sj < 4; ++sj)
      bv[sj] = *reinterpret_cast<const short8v*>(&xs[(sj * 16 + lr) * LDSW0_ + lg * 8]);
    #pragma unroll
    for (int ai = 0; ai < 4; ++ai)
      #pragma unroll
      for (int sj = 0; sj < 4; ++sj)
        acc[ai][sj] = __builtin_amdgcn_mfma_f32_16x16x32_bf16(a[ai], bv[sj], acc[ai][sj], 0, 0, 0);
  }
  float* outb = out + (size_t)b * COUT_ * LHW_ + l0;
  #pragma unroll
  for (int ai = 0; ai < 4; ++ai)
    #pragma unroll
    for (int r = 0; r < 4; ++r) {
      const int o = wid * 64 + ai * 16 + lg * 4 + r;
      const float bvs = bias[o];
      #pragma unroll
      for (int sj = 0; sj < 4; ++sj)
        outb[(size_t)o * LHW_ + sj * 16 + lr] = acc[ai][sj][r] + bvs;
    }
}

extern "C" void kernel_launch(void* const* d_in, const int* in_sizes, int n_in,
                              void* d_out, int out_size, void* d_ws, size_t ws_size,
                              hipStream_t stream) {
  (void)in_sizes; (void)n_in; (void)out_size;
  const float* in   = (const float*)d_in[0];
  const float* w    = (const float*)d_in[1];
  const float* bias = (const float*)d_in[2];
  float* out = (float*)d_out;

  const size_t wbytes = (size_t)COUT_ * KTOT_ * sizeof(u16);   // 589824
  if (ws_size >= wbytes) {
    u16* wb = (u16*)d_ws;
    wreorder_kernel<<<dim3(288), dim3(256), 0, stream>>>(w, wb);
    conv2_kernel<<<dim3(896), dim3(256), 0, stream>>>(in, wb, bias, out);
  } else {
    conv_fb_kernel<<<dim3(784), dim3(256), 0, stream>>>(in, w, bias, out);
  }
}

// Round 3
// 64.503 us; speedup vs baseline: 2.0503x; 1.1015x over previous
//
#include <hip/hip_runtime.h>
#include <hip/hip_bf16.h>

// 3x3 s1 p1 conv: B=16, CIN=128, H=W=56, COUT=256, K = 9*128.
// Pipeline: (1) wreorder: W fp32 [o][c*9+t] -> bf16 wb[t][o][c] (+ zero page)
//           (2) nhwc:     X fp32 NCHW -> bf16 NHWC xin[b][y][x][c]
//           (3) conv3:    implicit GEMM, global_load_lds staging with
//               pre-swizzled source, barrier-free 9-tap MFMA loop.
#define CIN_   128
#define HW_    56
#define LHW_   3136
#define COUT_  256
#define KTOT_  1152
#define TH_    2         // output rows per block tile
#define SPT_   112       // TH*56 spatial positions per block
#define NF_    7         // spatial N-fragments (112/16)
#define SCOLS_ 58        // staged cols (56 + 2 zero-pad)
#define SPP_   232       // staged positions (TH+2)*58
#define CSTR_  128       // u16 per staged row (all channels)

typedef unsigned short u16;
typedef __attribute__((ext_vector_type(8))) short short8v;   // 8 bf16
typedef __attribute__((ext_vector_type(4))) float f32x4;

__device__ __forceinline__ u16 f2bf(float f) {
  union { float f; unsigned u; } v; v.f = f;
  unsigned u = v.u;
  u += 0x7fffu + ((u >> 16) & 1u);   // RNE
  return (u16)(u >> 16);
}
__device__ __forceinline__ unsigned pack2(u16 a, u16 b) {
  return (unsigned)a | ((unsigned)b << 16);
}

// ---- (1) weight reorder: wb[(t*256+o)*128 + c] = bf16(w[o][c*9+t]) + zero page
__global__ void wreorder_kernel(const float* __restrict__ w, u16* __restrict__ wb,
                                u16* __restrict__ zp) {
  if (zp && blockIdx.x == 0 && threadIdx.x < 16) {
    uint4 z; z.x = z.y = z.z = z.w = 0u;
    reinterpret_cast<uint4*>(zp)[threadIdx.x] = z;   // 256B zero page
  }
  int j = blockIdx.x * 256 + threadIdx.x;   // 73728 = 9*256*32
  int c4 = j & 31;
  int o  = (j >> 5) & 255;
  int t  = j >> 13;
  const float* src = w + (size_t)o * KTOT_ + t;
  ushort4 r;
  r.x = f2bf(src[(c4 * 4 + 0) * 9]);
  r.y = f2bf(src[(c4 * 4 + 1) * 9]);
  r.z = f2bf(src[(c4 * 4 + 2) * 9]);
  r.w = f2bf(src[(c4 * 4 + 3) * 9]);
  *reinterpret_cast<ushort4*>(wb + ((size_t)(t * 256 + o) * CSTR_ + c4 * 4)) = r;
}

// ---- (2) NCHW fp32 -> NHWC bf16 transpose (LDS-tiled, 64 pos x 128 ch)
#define TLDSW_ 136   // u16 row stride (272B: 16B-aligned, odd-dword banked)
__global__ __launch_bounds__(256) void nhwc_kernel(
    const float* __restrict__ in, u16* __restrict__ xin) {
  __shared__ u16 ts[64 * TLDSW_];
  const int bp = blockIdx.x;          // 784 = 16 * 49
  const int b = bp / 49;
  const int pos0 = (bp % 49) * 64;
  const int tid = threadIdx.x;
  const float* ib = in + (size_t)b * CIN_ * LHW_ + pos0;
  {
    const int p  = tid & 63;
    const int c0 = (tid >> 6) * 32;
    #pragma unroll
    for (int i = 0; i < 32; ++i)
      ts[p * TLDSW_ + c0 + i] = f2bf(ib[(size_t)(c0 + i) * LHW_ + p]);
  }
  __syncthreads();
  {
    const int p  = tid >> 2;
    const int c0 = (tid & 3) * 32;
    u16* dst = xin + ((size_t)b * LHW_ + pos0 + p) * CIN_ + c0;
    const u16* srcr = &ts[p * TLDSW_ + c0];
    #pragma unroll
    for (int j = 0; j < 4; ++j)
      reinterpret_cast<uint4*>(dst)[j] =
          *reinterpret_cast<const uint4*>(srcr + j * 8);
  }
}

// ---- (3) main conv
__device__ __forceinline__ void gload_lds16(const void* g, void* l) {
  __builtin_amdgcn_global_load_lds(
      (const __attribute__((address_space(1))) void*)g,
      (__attribute__((address_space(3))) void*)l, 16, 0, 0);
}

__global__ __launch_bounds__(512, 4) void conv3_kernel(
    const u16* __restrict__ xin, const u16* __restrict__ wb,
    const float* __restrict__ bias, const u16* __restrict__ zpage,
    float* __restrict__ out)
{
  __shared__ u16 xs[SPP_ * CSTR_];   // 59392 B

  const int tid  = threadIdx.x;
  const int lane = tid & 63;
  const int wid  = tid >> 6;      // 0..7 -> 32-cout slice
  const int lr   = lane & 15;
  const int lg   = lane >> 4;

  const int swz = (blockIdx.x & 7) * 56 + (blockIdx.x >> 3);  // 448 = 8*56, bijective
  const int b   = swz / 28;
  const int ty  = swz % 28;
  const int iy0 = ty * TH_ - 1;

  const u16* xb = xin + (size_t)b * LHW_ * CIN_;

  // staging: 3712 16B chunks; LDS linear, source pre-swizzled (chunk ^ spp&7)
  auto stage_one = [&](int idx) {
    int spp   = idx >> 4;
    int chunk = idx & 15;
    int rr = spp / SCOLS_;
    int cc = spp - rr * SCOLS_;
    int iy = iy0 + rr;
    int ix = cc - 1;
    int sch = chunk ^ (spp & 7);
    const u16* src =
        ((unsigned)iy < (unsigned)HW_ && (unsigned)ix < (unsigned)HW_)
            ? xb + ((size_t)(iy * HW_ + ix) * CIN_ + sch * 8)
            : zpage;
    u16* ldst = xs + (size_t)(idx & ~63) * 8;   // wave-uniform base
    gload_lds16(src, ldst);
  };
  #pragma unroll
  for (int i = 0; i < 7; ++i) stage_one(i * 512 + tid);
  if (tid < 128) stage_one(3584 + tid);         // wave-uniform tail (waves 0-1)

  // per-lane staged-position base per N-fragment
  int spp0[NF_];
  #pragma unroll
  for (int nf = 0; nf < NF_; ++nf) {
    int sp = nf * 16 + lr;
    int r  = (sp >= 56) ? 1 : 0;
    int x  = sp - r * 56;
    spp0[nf] = (r + 1) * SCOLS_ + (x + 1);
  }

  f32x4 acc[2][NF_];
  #pragma unroll
  for (int m = 0; m < 2; ++m)
    #pragma unroll
    for (int nf = 0; nf < NF_; ++nf)
      acc[m][nf] = f32x4{0.f, 0.f, 0.f, 0.f};

  __syncthreads();   // drains global_load_lds (vmcnt 0) — the only barrier

  const u16* wt0 = wb + (size_t)(wid * 32 + lr) * CSTR_ + lg * 8;

  #pragma unroll
  for (int t = 0; t < 9; ++t) {
    const int dspp = (t / 3 - 1) * SCOLS_ + (t % 3 - 1);
    const u16* wt = wt0 + (size_t)t * COUT_ * CSTR_;
    #pragma unroll
    for (int c0i = 0; c0i < 4; ++c0i) {
      const int c0 = c0i * 32;
      short8v a0 = *reinterpret_cast<const short8v*>(wt + c0);
      short8v a1 = *reinterpret_cast<const short8v*>(wt + 16 * CSTR_ + c0);
      short8v bv[NF_];
      #pragma unroll
      for (int nf = 0; nf < NF_; ++nf) {
        int spp = spp0[nf] + dspp;
        int off = (spp << 7) + ((c0 + lg * 8) ^ ((spp & 7) << 3));
        bv[nf] = *reinterpret_cast<const short8v*>(&xs[off]);
      }
      #pragma unroll
      for (int nf = 0; nf < NF_; ++nf) {
        acc[0][nf] = __builtin_amdgcn_mfma_f32_16x16x32_bf16(a0, bv[nf], acc[0][nf], 0, 0, 0);
        acc[1][nf] = __builtin_amdgcn_mfma_f32_16x16x32_bf16(a1, bv[nf], acc[1][nf], 0, 0, 0);
      }
    }
  }

  // epilogue: D col = lr (spatial), row = lg*4+reg (cout); spatial is linear.
  float* ob = out + (size_t)b * COUT_ * LHW_ + ty * SPT_;
  const int obase = wid * 32 + lg * 4;
  #pragma unroll
  for (int m = 0; m < 2; ++m) {
    #pragma unroll
    for (int rr = 0; rr < 4; ++rr) {
      const int o = obase + m * 16 + rr;
      const float bs = bias[o];
      #pragma unroll
      for (int nf = 0; nf < NF_; ++nf)
        ob[(size_t)o * LHW_ + nf * 16 + lr] = acc[m][nf][rr] + bs;
    }
  }
}

// ---------------- fallback A (ws fits wb only): round-2 kernel ----
__global__ __launch_bounds__(256, 2) void conv2_kernel(
    const float* __restrict__ in, const u16* __restrict__ wb,
    const float* __restrict__ bias, float* __restrict__ out)
{
  __shared__ u16 xs[SPP_ * CSTR_];
  const int tid  = threadIdx.x;
  const int lane = tid & 63;
  const int wid  = tid >> 6;
  const int lr   = lane & 15;
  const int lg   = lane >> 4;
  const int bid = blockIdx.x;
  const int ch  = bid & 1;
  const int ty  = (bid >> 1) % 28;
  const int b   = bid / 56;
  const float* inb = in + (size_t)b * CIN_ * LHW_;
  const int iy0 = ty * TH_ - 1;

  #pragma unroll 1
  for (int i = 0; i < 15; ++i) {
    int idx = i * 256 + tid;
    if (idx < SPP_ * 16) {
      int cg  = idx / SPP_;
      int spp = idx - cg * SPP_;
      int rr  = spp / SCOLS_;
      int cc  = spp - rr * SCOLS_;
      int iy  = iy0 + rr;
      int ix  = cc - 1;
      bool ok = ((unsigned)iy < (unsigned)HW_) && ((unsigned)ix < (unsigned)HW_);
      const float* p = inb + (size_t)cg * 8 * LHW_ + iy * HW_ + ix;
      u16 v[8];
      #pragma unroll
      for (int jj = 0; jj < 8; ++jj)
        v[jj] = f2bf(ok ? p[jj * LHW_] : 0.f);
      uint4 pk;
      pk.x = pack2(v[0], v[1]); pk.y = pack2(v[2], v[3]);
      pk.z = pack2(v[4], v[5]); pk.w = pack2(v[6], v[7]);
      *reinterpret_cast<uint4*>(&xs[spp * CSTR_ + ((cg * 8) ^ ((spp & 7) << 3))]) = pk;
    }
  }
  int spp0[NF_];
  #pragma unroll
  for (int nf = 0; nf < NF_; ++nf) {
    int sp = nf * 16 + lr;
    int r  = (sp >= 56) ? 1 : 0;
    int x  = sp - r * 56;
    spp0[nf] = (r + 1) * SCOLS_ + x + 1;
  }
  f32x4 acc[2][NF_];
  #pragma unroll
  for (int m = 0; m < 2; ++m)
    #pragma unroll
    for (int nf = 0; nf < NF_; ++nf)
      acc[m][nf] = f32x4{0.f, 0.f, 0.f, 0.f};
  __syncthreads();
  const u16* wt0 = wb + (size_t)(ch * 128 + wid * 32 + lr) * CSTR_ + lg * 8;
  #pragma unroll 1
  for (int t = 0; t < 9; ++t) {
    const int dspp = (t / 3 - 1) * SCOLS_ + (t % 3 - 1);
    const u16* wt = wt0 + (size_t)t * 256 * CSTR_;
    #pragma unroll
    for (int c0i = 0; c0i < 4; ++c0i) {
      const int c0 = c0i * 32;
      short8v a0 = *reinterpret_cast<const short8v*>(wt + c0);
      short8v a1 = *reinterpret_cast<const short8v*>(wt + 16 * CSTR_ + c0);
      short8v bv[NF_];
      #pragma unroll
      for (int nf = 0; nf < NF_; ++nf) {
        int spp = spp0[nf] + dspp;
        int off = spp * CSTR_ + ((c0 + lg * 8) ^ ((spp & 7) << 3));
        bv[nf] = *reinterpret_cast<const short8v*>(&xs[off]);
      }
      #pragma unroll
      for (int nf = 0; nf < NF_; ++nf) {
        acc[0][nf] = __builtin_amdgcn_mfma_f32_16x16x32_bf16(a0, bv[nf], acc[0][nf], 0, 0, 0);
        acc[1][nf] = __builtin_amdgcn_mfma_f32_16x16x32_bf16(a1, bv[nf], acc[1][nf], 0, 0, 0);
      }
    }
  }
  float* ob = out + (size_t)b * COUT_ * LHW_ + ty * SPT_;
  const int obase = ch * 128 + wid * 32 + lg * 4;
  #pragma unroll
  for (int m = 0; m < 2; ++m)
    #pragma unroll
    for (int rr = 0; rr < 4; ++rr) {
      const int o = obase + m * 16 + rr;
      const float bs = bias[o];
      #pragma unroll
      for (int nf = 0; nf < NF_; ++nf)
        ob[(size_t)o * LHW_ + nf * 16 + lr] = acc[m][nf][rr] + bs;
    }
}

// ---------------- fallback B (no ws at all): fp32-weight direct ----
#define SPT0_  64
#define BK0_   32
#define NKS0_  36
#define LDSW0_ 40
__global__ __launch_bounds__(256, 2) void conv_fb_kernel(
    const float* __restrict__ in, const float* __restrict__ wf,
    const float* __restrict__ bias, float* __restrict__ out)
{
  __shared__ u16 xs[SPT0_ * LDSW0_];
  const int tid = threadIdx.x;
  const int lane = tid & 63;
  const int wid = tid >> 6;
  const int lg = lane >> 4;
  const int lr = lane & 15;
  const int bid = blockIdx.x;
  const int b = bid / 49;
  const int l0 = (bid % 49) * SPT0_;
  const int sp = tid & 63;
  const int qq = tid >> 6;
  const int l = l0 + sp;
  const int y = l / HW_;
  const int x = l - y * HW_;
  const float* inb = in + (size_t)b * CIN_ * LHW_;
  f32x4 acc[4][4];
  #pragma unroll
  for (int i = 0; i < 4; ++i)
    #pragma unroll
    for (int j = 0; j < 4; ++j) acc[i][j] = f32x4{0.f, 0.f, 0.f, 0.f};
  auto stage_load = [&](int ks) -> uint4 {
    int kbase = ks * BK0_ + qq * 8;
    int c = kbase / 9;
    int t = kbase - c * 9;
    u16 v[8];
    #pragma unroll
    for (int j = 0; j < 8; ++j) {
      int dy = (t * 11) >> 5;
      int dx = t - 3 * dy;
      int yy = y + dy - 1, xx = x + dx - 1;
      float f = 0.f;
      if ((unsigned)yy < (unsigned)HW_ && (unsigned)xx < (unsigned)HW_)
        f = inb[(c * HW_ + yy) * HW_ + xx];
      v[j] = f2bf(f);
      ++t; if (t == 9) { t = 0; ++c; }
    }
    uint4 r;
    r.x = pack2(v[0], v[1]); r.y = pack2(v[2], v[3]);
    r.z = pack2(v[4], v[5]); r.w = pack2(v[6], v[7]);
    return r;
  };
  uint4 st = stage_load(0);
  for (int ks = 0; ks < NKS0_; ++ks) {
    __syncthreads();
    *reinterpret_cast<uint4*>(&xs[sp * LDSW0_ + qq * 8]) = st;
    __syncthreads();
    if (ks + 1 < NKS0_) st = stage_load(ks + 1);
    const int k0 = ks * BK0_;
    short8v a[4];
    #pragma unroll
    for (int ai = 0; ai < 4; ++ai) {
      const int o = wid * 64 + ai * 16 + lr;
      const float* p = wf + (size_t)o * KTOT_ + k0 + lg * 8;
      u16 t8[8];
      #pragma unroll
      for (int j = 0; j < 8; ++j) t8[j] = f2bf(p[j]);
      union { uint4 u; short8v s; } cv;
      cv.u.x = pack2(t8[0], t8[1]); cv.u.y = pack2(t8[2], t8[3]);
      cv.u.z = pack2(t8[4], t8[5]); cv.u.w = pack2(t8[6], t8[7]);
      a[ai] = cv.s;
    }
    short8v bv[4];
    #pragma unroll
    for (int sj = 0; sj < 4; ++sj)
      bv[sj] = *reinterpret_cast<const short8v*>(&xs[(sj * 16 + lr) * LDSW0_ + lg * 8]);
    #pragma unroll
    for (int ai = 0; ai < 4; ++ai)
      #pragma unroll
      for (int sj = 0; sj < 4; ++sj)
        acc[ai][sj] = __builtin_amdgcn_mfma_f32_16x16x32_bf16(a[ai], bv[sj], acc[ai][sj], 0, 0, 0);
  }
  float* outb = out + (size_t)b * COUT_ * LHW_ + l0;
  #pragma unroll
  for (int ai = 0; ai < 4; ++ai)
    #pragma unroll
    for (int r = 0; r < 4; ++r) {
      const int o = wid * 64 + ai * 16 + lg * 4 + r;
      const float bvs = bias[o];
      #pragma unroll
      for (int sj = 0; sj < 4; ++sj)
        outb[(size_t)o * LHW_ + sj * 16 + lr] = acc[ai][sj][r] + bvs;
    }
}

extern "C" void kernel_launch(void* const* d_in, const int* in_sizes, int n_in,
                              void* d_out, int out_size, void* d_ws, size_t ws_size,
                              hipStream_t stream) {
  (void)in_sizes; (void)n_in; (void)out_size;
  const float* in   = (const float*)d_in[0];
  const float* w    = (const float*)d_in[1];
  const float* bias = (const float*)d_in[2];
  float* out = (float*)d_out;

  const size_t wbytes  = (size_t)COUT_ * KTOT_ * sizeof(u16);        // 589824
  const size_t xbytes  = (size_t)16 * LHW_ * CIN_ * sizeof(u16);     // 12845056
  const size_t need    = wbytes + xbytes + 256;

  if (ws_size >= need) {
    u16* wb  = (u16*)d_ws;
    u16* xin = wb + wbytes / 2;
    u16* zp  = xin + xbytes / 2;
    wreorder_kernel<<<dim3(288), dim3(256), 0, stream>>>(w, wb, zp);
    nhwc_kernel<<<dim3(784), dim3(256), 0, stream>>>(in, xin);
    conv3_kernel<<<dim3(448), dim3(512), 0, stream>>>(xin, wb, bias, zp, out);
  } else if (ws_size >= wbytes) {
    u16* wb = (u16*)d_ws;
    wreorder_kernel<<<dim3(288), dim3(256), 0, stream>>>(w, wb, nullptr);
    conv2_kernel<<<dim3(896), dim3(256), 0, stream>>>(in, wb, bias, out);
  } else {
    conv_fb_kernel<<<dim3(784), dim3(256), 0, stream>>>(in, w, bias, out);
  }
}

// Round 4
// 61.774 us; speedup vs baseline: 2.1409x; 1.0442x over previous
//
#include <hip/hip_runtime.h>
#include <hip/hip_bf16.h>

// 3x3 s1 p1 conv: B=16, CIN=128, H=W=56, COUT=256, K = 9*128.
// Pipeline: (1) wreorder2: W fp32 [o][c*9+t] -> bf16 frag-major wb2 (+zero page)
//           (2) nhwc:      X fp32 NCHW -> bf16 NHWC xin[b][y][x][c]
//           (3) conv4:     implicit GEMM, 224 blocks x 512 thr, wave=64co x 112sp,
//                          rotating A/B double-buffer, barrier-free 9-tap loop.
#define CIN_   128
#define HW_    56
#define LHW_   3136
#define COUT_  256
#define KTOT_  1152
#define TH4_   4         // output rows per block
#define SPB_   224       // spatial positions per block
#define NF_    7         // n-frags per wave (112/16)
#define SCOLS_ 58
#define SPP4_  348       // (TH4+2)*58 staged positions
#define CSTR_  128       // u16 per staged row

typedef unsigned short u16;
typedef __attribute__((ext_vector_type(8))) short short8v;   // 8 bf16
typedef __attribute__((ext_vector_type(4))) float f32x4;

__device__ __forceinline__ u16 f2bf(float f) {
  union { float f; unsigned u; } v; v.f = f;
  unsigned u = v.u;
  u += 0x7fffu + ((u >> 16) & 1u);   // RNE
  return (u16)(u >> 16);
}
__device__ __forceinline__ unsigned pack2(u16 a, u16 b) {
  return (unsigned)a | ((unsigned)b << 16);
}

// ---- (1) frag-major weight reorder + zero page.
// short8v slot ((t*4+c0i)*16 + o>>4)*64 + lg*16 + (o&15) holds
// w[o][c(=c0i*32+lg*8 ..+8)*9 + t] as bf16.
__global__ void wreorder2_kernel(const float* __restrict__ w, u16* __restrict__ wb,
                                 u16* __restrict__ zp) {
  if (blockIdx.x == 0 && threadIdx.x < 16) {
    uint4 z; z.x = z.y = z.z = z.w = 0u;
    reinterpret_cast<uint4*>(zp)[threadIdx.x] = z;   // 256B zero page
  }
  int j = blockIdx.x * 256 + threadIdx.x;   // 73728 = 9*256*32
  int c4 = j & 31;                           // c-quad: c = c4*4..+3
  int o  = (j >> 5) & 255;
  int t  = j >> 13;
  int c0i = c4 >> 3;
  int lg  = (c4 >> 1) & 3;
  size_t slot = ((size_t)(t * 4 + c0i) * 16 + (o >> 4)) * 64 + lg * 16 + (o & 15);
  const float* src = w + (size_t)o * KTOT_ + t;
  ushort4 r;
  r.x = f2bf(src[(c4 * 4 + 0) * 9]);
  r.y = f2bf(src[(c4 * 4 + 1) * 9]);
  r.z = f2bf(src[(c4 * 4 + 2) * 9]);
  r.w = f2bf(src[(c4 * 4 + 3) * 9]);
  *reinterpret_cast<ushort4*>(wb + slot * 8 + (c4 & 1) * 4) = r;
}

// ---- legacy weight reorder for fallback A: wb[(t*256+o)*128 + c]
__global__ void wreorder_kernel(const float* __restrict__ w, u16* __restrict__ wb) {
  int j = blockIdx.x * 256 + threadIdx.x;
  int c4 = j & 31;
  int o  = (j >> 5) & 255;
  int t  = j >> 13;
  const float* src = w + (size_t)o * KTOT_ + t;
  ushort4 r;
  r.x = f2bf(src[(c4 * 4 + 0) * 9]);
  r.y = f2bf(src[(c4 * 4 + 1) * 9]);
  r.z = f2bf(src[(c4 * 4 + 2) * 9]);
  r.w = f2bf(src[(c4 * 4 + 3) * 9]);
  *reinterpret_cast<ushort4*>(wb + ((size_t)(t * 256 + o) * CSTR_ + c4 * 4)) = r;
}

// ---- (2) NCHW fp32 -> NHWC bf16 transpose (LDS-tiled, 64 pos x 128 ch)
#define TLDSW_ 136
__global__ __launch_bounds__(256) void nhwc_kernel(
    const float* __restrict__ in, u16* __restrict__ xin) {
  __shared__ u16 ts[64 * TLDSW_];
  const int bp = blockIdx.x;          // 784 = 16 * 49
  const int b = bp / 49;
  const int pos0 = (bp % 49) * 64;
  const int tid = threadIdx.x;
  const float* ib = in + (size_t)b * CIN_ * LHW_ + pos0;
  {
    const int p  = tid & 63;
    const int c0 = (tid >> 6) * 32;
    #pragma unroll
    for (int i = 0; i < 32; ++i)
      ts[p * TLDSW_ + c0 + i] = f2bf(ib[(size_t)(c0 + i) * LHW_ + p]);
  }
  __syncthreads();
  {
    const int p  = tid >> 2;
    const int c0 = (tid & 3) * 32;
    u16* dst = xin + ((size_t)b * LHW_ + pos0 + p) * CIN_ + c0;
    const u16* srcr = &ts[p * TLDSW_ + c0];
    #pragma unroll
    for (int j = 0; j < 4; ++j)
      reinterpret_cast<uint4*>(dst)[j] =
          *reinterpret_cast<const uint4*>(srcr + j * 8);
  }
}

// ---- (3) main conv
__device__ __forceinline__ void gload_lds16(const void* g, void* l) {
  __builtin_amdgcn_global_load_lds(
      (const __attribute__((address_space(1))) void*)g,
      (__attribute__((address_space(3))) void*)l, 16, 0, 0);
}

__global__ __launch_bounds__(512, 2) void conv4_kernel(
    const u16* __restrict__ xin, const u16* __restrict__ wb2,
    const float* __restrict__ bias, const u16* __restrict__ zpage,
    float* __restrict__ out)
{
  __shared__ u16 xs[SPP4_ * CSTR_];   // 89088 B

  const int tid  = threadIdx.x;
  const int lane = tid & 63;
  const int wid  = tid >> 6;      // 0..7
  const int wc   = wid & 3;       // 64-cout slice
  const int ws   = wid >> 2;      // 112-sp half
  const int lr   = lane & 15;
  const int lg   = lane >> 4;
  const int lg8  = lg * 8;

  const int ty = blockIdx.x % 14;
  const int b  = blockIdx.x / 14;
  const int iy0 = ty * TH4_ - 1;

  const u16* xb = xin + (size_t)b * LHW_ * CIN_;

  // ---- staging: 5568 16B chunks, LDS linear, source pre-swizzled ----
  #pragma unroll
  for (int i = 0; i < 11; ++i) {
    int idx = i * 512 + tid;
    if (idx < SPP4_ * 16) {                 // wave-uniform guard
      int spp   = idx >> 4;
      int chunk = idx & 15;
      int rr = spp / SCOLS_;
      int cc = spp - rr * SCOLS_;
      int iy = iy0 + rr;
      int ix = cc - 1;
      int sch = chunk ^ (spp & 7);
      const u16* src =
          ((unsigned)iy < (unsigned)HW_ && (unsigned)ix < (unsigned)HW_)
              ? xb + ((size_t)(iy * HW_ + ix) * CIN_ + sch * 8)
              : zpage;
      u16* ldst = xs + (size_t)(idx & ~63) * 8;   // wave-uniform base
      gload_lds16(src, ldst);
    }
  }

  // per-lane staged-position base per N-fragment
  int spp0[NF_];
  #pragma unroll
  for (int nf = 0; nf < NF_; ++nf) {
    int sp = ws * 112 + nf * 16 + lr;       // 0..223
    int r  = sp / 56;
    int x  = sp - r * 56;
    spp0[nf] = (r + 1) * SCOLS_ + (x + 1);
  }

  f32x4 acc[4][NF_];
  #pragma unroll
  for (int m = 0; m < 4; ++m)
    #pragma unroll
    for (int nf = 0; nf < NF_; ++nf)
      acc[m][nf] = f32x4{0.f, 0.f, 0.f, 0.f};

  __syncthreads();   // drains global_load_lds — the only barrier

  const short8v* pA = reinterpret_cast<const short8v*>(wb2);

  auto loadA = [&](int t4c, short8v* dst) {
    const short8v* p = pA + ((size_t)t4c * 16 + wc * 4) * 64 + lane;
    #pragma unroll
    for (int ai = 0; ai < 4; ++ai) dst[ai] = p[ai * 64];
  };
  auto loadB = [&](int dspp, int c0, short8v* dst) {
    #pragma unroll
    for (int nf = 0; nf < NF_; ++nf) {
      int spp = spp0[nf] + dspp;
      int off = (spp << 7) + ((c0 + lg8) ^ ((spp & 7) << 3));
      dst[nf] = *reinterpret_cast<const short8v*>(&xs[off]);
    }
  };

  short8v A0[4], A1[4], B0[NF_], B1[NF_];

#define MFMA_GRP(Ab, Bb)                                                        \
  {                                                                             \
    _Pragma("unroll")                                                           \
    for (int ai = 0; ai < 4; ++ai) {                                            \
      _Pragma("unroll")                                                         \
      for (int nf = 0; nf < NF_; ++nf)                                          \
        acc[ai][nf] = __builtin_amdgcn_mfma_f32_16x16x32_bf16(                  \
            (Ab)[ai], (Bb)[nf], acc[ai][nf], 0, 0, 0);                          \
    }                                                                           \
  }

  loadA(0, A0);
  loadB(-SCOLS_ - 1, 0, B0);      // dspp(t=0) = -59

  #pragma unroll 1
  for (int t = 0; t < 9; ++t) {
    const int dty  = t / 3;
    const int dspp = (dty - 1) * SCOLS_ + (t - 3 * dty) - 1;
    const int t4   = t * 4;

    loadA(t4 + 1, A1); loadB(dspp, 32, B1);
    MFMA_GRP(A0, B0);
    loadA(t4 + 2, A0); loadB(dspp, 64, B0);
    MFMA_GRP(A1, B1);
    loadA(t4 + 3, A1); loadB(dspp, 96, B1);
    MFMA_GRP(A0, B0);
    if (t < 8) {
      const int tn   = t + 1;
      const int ndty = tn / 3;
      const int nds  = (ndty - 1) * SCOLS_ + (tn - 3 * ndty) - 1;
      loadA(t4 + 4, A0); loadB(nds, 0, B0);
    }
    MFMA_GRP(A1, B1);
  }

  // epilogue: D col = lr (spatial), row = lg*4+reg (cout); spatial linear.
  float* ob = out + (size_t)b * COUT_ * LHW_ + ty * SPB_ + ws * 112;
  const int obase = wc * 64 + lg * 4;
  #pragma unroll
  for (int ai = 0; ai < 4; ++ai) {
    #pragma unroll
    for (int rr = 0; rr < 4; ++rr) {
      const int o = obase + ai * 16 + rr;
      const float bs = bias[o];
      #pragma unroll
      for (int nf = 0; nf < NF_; ++nf)
        ob[(size_t)o * LHW_ + nf * 16 + lr] = acc[ai][nf][rr] + bs;
    }
  }
#undef MFMA_GRP
}

// ---------------- fallback A (ws fits wb only): round-2 kernel ----
#define TH_    2
#define SPT_   112
#define SPP_   232
__global__ __launch_bounds__(256, 2) void conv2_kernel(
    const float* __restrict__ in, const u16* __restrict__ wb,
    const float* __restrict__ bias, float* __restrict__ out)
{
  __shared__ u16 xs[SPP_ * CSTR_];
  const int tid  = threadIdx.x;
  const int lane = tid & 63;
  const int wid  = tid >> 6;
  const int lr   = lane & 15;
  const int lg   = lane >> 4;
  const int bid = blockIdx.x;
  const int ch  = bid & 1;
  const int ty  = (bid >> 1) % 28;
  const int b   = bid / 56;
  const float* inb = in + (size_t)b * CIN_ * LHW_;
  const int iy0 = ty * TH_ - 1;

  #pragma unroll 1
  for (int i = 0; i < 15; ++i) {
    int idx = i * 256 + tid;
    if (idx < SPP_ * 16) {
      int cg  = idx / SPP_;
      int spp = idx - cg * SPP_;
      int rr  = spp / SCOLS_;
      int cc  = spp - rr * SCOLS_;
      int iy  = iy0 + rr;
      int ix  = cc - 1;
      bool ok = ((unsigned)iy < (unsigned)HW_) && ((unsigned)ix < (unsigned)HW_);
      const float* p = inb + (size_t)cg * 8 * LHW_ + iy * HW_ + ix;
      u16 v[8];
      #pragma unroll
      for (int jj = 0; jj < 8; ++jj)
        v[jj] = f2bf(ok ? p[jj * LHW_] : 0.f);
      uint4 pk;
      pk.x = pack2(v[0], v[1]); pk.y = pack2(v[2], v[3]);
      pk.z = pack2(v[4], v[5]); pk.w = pack2(v[6], v[7]);
      *reinterpret_cast<uint4*>(&xs[spp * CSTR_ + ((cg * 8) ^ ((spp & 7) << 3))]) = pk;
    }
  }
  int spp0[NF_];
  #pragma unroll
  for (int nf = 0; nf < NF_; ++nf) {
    int sp = nf * 16 + lr;
    int r  = (sp >= 56) ? 1 : 0;
    int x  = sp - r * 56;
    spp0[nf] = (r + 1) * SCOLS_ + x + 1;
  }
  f32x4 acc[2][NF_];
  #pragma unroll
  for (int m = 0; m < 2; ++m)
    #pragma unroll
    for (int nf = 0; nf < NF_; ++nf)
      acc[m][nf] = f32x4{0.f, 0.f, 0.f, 0.f};
  __syncthreads();
  const u16* wt0 = wb + (size_t)(ch * 128 + wid * 32 + lr) * CSTR_ + lg * 8;
  #pragma unroll 1
  for (int t = 0; t < 9; ++t) {
    const int dspp = (t / 3 - 1) * SCOLS_ + (t % 3 - 1);
    const u16* wt = wt0 + (size_t)t * 256 * CSTR_;
    #pragma unroll
    for (int c0i = 0; c0i < 4; ++c0i) {
      const int c0 = c0i * 32;
      short8v a0 = *reinterpret_cast<const short8v*>(wt + c0);
      short8v a1 = *reinterpret_cast<const short8v*>(wt + 16 * CSTR_ + c0);
      short8v bv[NF_];
      #pragma unroll
      for (int nf = 0; nf < NF_; ++nf) {
        int spp = spp0[nf] + dspp;
        int off = spp * CSTR_ + ((c0 + lg * 8) ^ ((spp & 7) << 3));
        bv[nf] = *reinterpret_cast<const short8v*>(&xs[off]);
      }
      #pragma unroll
      for (int nf = 0; nf < NF_; ++nf) {
        acc[0][nf] = __builtin_amdgcn_mfma_f32_16x16x32_bf16(a0, bv[nf], acc[0][nf], 0, 0, 0);
        acc[1][nf] = __builtin_amdgcn_mfma_f32_16x16x32_bf16(a1, bv[nf], acc[1][nf], 0, 0, 0);
      }
    }
  }
  float* ob = out + (size_t)b * COUT_ * LHW_ + ty * SPT_;
  const int obase = ch * 128 + wid * 32 + lg * 4;
  #pragma unroll
  for (int m = 0; m < 2; ++m)
    #pragma unroll
    for (int rr = 0; rr < 4; ++rr) {
      const int o = obase + m * 16 + rr;
      const float bs = bias[o];
      #pragma unroll
      for (int nf = 0; nf < NF_; ++nf)
        ob[(size_t)o * LHW_ + nf * 16 + lr] = acc[m][nf][rr] + bs;
    }
}

// ---------------- fallback B (no ws at all): fp32-weight direct ----
#define SPT0_  64
#define BK0_   32
#define NKS0_  36
#define LDSW0_ 40
__global__ __launch_bounds__(256, 2) void conv_fb_kernel(
    const float* __restrict__ in, const float* __restrict__ wf,
    const float* __restrict__ bias, float* __restrict__ out)
{
  __shared__ u16 xs[SPT0_ * LDSW0_];
  const int tid = threadIdx.x;
  const int lane = tid & 63;
  const int wid = tid >> 6;
  const int lg = lane >> 4;
  const int lr = lane & 15;
  const int bid = blockIdx.x;
  const int b = bid / 49;
  const int l0 = (bid % 49) * SPT0_;
  const int sp = tid & 63;
  const int qq = tid >> 6;
  const int l = l0 + sp;
  const int y = l / HW_;
  const int x = l - y * HW_;
  const float* inb = in + (size_t)b * CIN_ * LHW_;
  f32x4 acc[4][4];
  #pragma unroll
  for (int i = 0; i < 4; ++i)
    #pragma unroll
    for (int j = 0; j < 4; ++j) acc[i][j] = f32x4{0.f, 0.f, 0.f, 0.f};
  auto stage_load = [&](int ks) -> uint4 {
    int kbase = ks * BK0_ + qq * 8;
    int c = kbase / 9;
    int t = kbase - c * 9;
    u16 v[8];
    #pragma unroll
    for (int j = 0; j < 8; ++j) {
      int dy = (t * 11) >> 5;
      int dx = t - 3 * dy;
      int yy = y + dy - 1, xx = x + dx - 1;
      float f = 0.f;
      if ((unsigned)yy < (unsigned)HW_ && (unsigned)xx < (unsigned)HW_)
        f = inb[(c * HW_ + yy) * HW_ + xx];
      v[j] = f2bf(f);
      ++t; if (t == 9) { t = 0; ++c; }
    }
    uint4 r;
    r.x = pack2(v[0], v[1]); r.y = pack2(v[2], v[3]);
    r.z = pack2(v[4], v[5]); r.w = pack2(v[6], v[7]);
    return r;
  };
  uint4 st = stage_load(0);
  for (int ks = 0; ks < NKS0_; ++ks) {
    __syncthreads();
    *reinterpret_cast<uint4*>(&xs[sp * LDSW0_ + qq * 8]) = st;
    __syncthreads();
    if (ks + 1 < NKS0_) st = stage_load(ks + 1);
    const int k0 = ks * BK0_;
    short8v a[4];
    #pragma unroll
    for (int ai = 0; ai < 4; ++ai) {
      const int o = wid * 64 + ai * 16 + lr;
      const float* p = wf + (size_t)o * KTOT_ + k0 + lg * 8;
      u16 t8[8];
      #pragma unroll
      for (int j = 0; j < 8; ++j) t8[j] = f2bf(p[j]);
      union { uint4 u; short8v s; } cv;
      cv.u.x = pack2(t8[0], t8[1]); cv.u.y = pack2(t8[2], t8[3]);
      cv.u.z = pack2(t8[4], t8[5]); cv.u.w = pack2(t8[6], t8[7]);
      a[ai] = cv.s;
    }
    short8v bv[4];
    #pragma unroll
    for (int sj = 0; sj < 4; ++sj)
      bv[sj] = *reinterpret_cast<const short8v*>(&xs[(sj * 16 + lr) * LDSW0_ + lg * 8]);
    #pragma unroll
    for (int ai = 0; ai < 4; ++ai)
      #pragma unroll
      for (int sj = 0; sj < 4; ++sj)
        acc[ai][sj] = __builtin_amdgcn_mfma_f32_16x16x32_bf16(a[ai], bv[sj], acc[ai][sj], 0, 0, 0);
  }
  float* outb = out + (size_t)b * COUT_ * LHW_ + l0;
  #pragma unroll
  for (int ai = 0; ai < 4; ++ai)
    #pragma unroll
    for (int r = 0; r < 4; ++r) {
      const int o = wid * 64 + ai * 16 + lg * 4 + r;
      const float bvs = bias[o];
      #pragma unroll
      for (int sj = 0; sj < 4; ++sj)
        outb[(size_t)o * LHW_ + sj * 16 + lr] = acc[ai][sj][r] + bvs;
    }
}

extern "C" void kernel_launch(void* const* d_in, const int* in_sizes, int n_in,
                              void* d_out, int out_size, void* d_ws, size_t ws_size,
                              hipStream_t stream) {
  (void)in_sizes; (void)n_in; (void)out_size;
  const float* in   = (const float*)d_in[0];
  const float* w    = (const float*)d_in[1];
  const float* bias = (const float*)d_in[2];
  float* out = (float*)d_out;

  const size_t wbytes  = (size_t)COUT_ * KTOT_ * sizeof(u16);        // 589824
  const size_t xbytes  = (size_t)16 * LHW_ * CIN_ * sizeof(u16);     // 12845056
  const size_t need    = wbytes + xbytes + 256;

  if (ws_size >= need) {
    u16* wb2 = (u16*)d_ws;
    u16* xin = wb2 + wbytes / 2;
    u16* zp  = xin + xbytes / 2;
    wreorder2_kernel<<<dim3(288), dim3(256), 0, stream>>>(w, wb2, zp);
    nhwc_kernel<<<dim3(784), dim3(256), 0, stream>>>(in, xin);
    conv4_kernel<<<dim3(224), dim3(512), 0, stream>>>(xin, wb2, bias, zp, out);
  } else if (ws_size >= wbytes) {
    u16* wb = (u16*)d_ws;
    wreorder_kernel<<<dim3(288), dim3(256), 0, stream>>>(w, wb);
    conv2_kernel<<<dim3(896), dim3(256), 0, stream>>>(in, wb, bias, out);
  } else {
    conv_fb_kernel<<<dim3(784), dim3(256), 0, stream>>>(in, w, bias, out);
  }
}